// Round 4
// baseline (93.260 us; speedup 1.0000x reference)
//
#include <hip/hip_runtime.h>
#include <math.h>

#define BLOCK 256
#define GRID  1024

__device__ __forceinline__ void walker_accum(
    float x0, float y0, float z0, float x1, float y1, float z1,
    float Z, float k1, float k2,
    float c1r, float c1i, float c2r, float c2i,
    double& s_hr, double& s_hi, double& s_pr, double& s_pi)
{
    float r0 = sqrtf(x0*x0 + y0*y0 + z0*z0);
    float r1 = sqrtf(x1*x1 + y1*y1 + z1*z1);
    float ir0 = 1.0f / r0;
    float ir1 = 1.0f / r1;

    // exp(-Z r) = h^2 with h = exp(-0.5 Z r): one expf per particle
    float h0 = expf(-0.5f * Z * r0);
    float h1 = expf(-0.5f * Z * r1);
    float e0 = h0 * h0;
    float e1 = h1 * h1;

    float psi1_0 = k1 * e0;
    float psi1_1 = k1 * e1;
    float psi2_0 = k2 * (2.0f - Z * r0) * h0;
    float psi2_1 = k2 * (2.0f - Z * r1) * h1;

    float Psi1 = psi1_0 * psi1_1;
    float Psi2 = psi2_0 * psi2_1;

    float sum_inv = ir0 + ir1;
    float lap1 = 2.0f * Z * Z - 2.0f * Z * sum_inv;   // n=1, two particles
    float lap2 = 0.5f * Z * Z - 2.0f * Z * sum_inv;   // n=2 (0.25 Z^2 each)

    float dx = x0 - x1, dy = y0 - y1, dz = z0 - z1;
    float d12 = sqrtf(dx*dx + dy*dy + dz*dz);
    float V = -1.0f / d12;                            // VB = 1

    float H1 = (-0.5f * lap1 + V) * Psi1;
    float H2 = (-0.5f * lap2 + V) * Psi2;

    float Hr = c1r * H1 + c2r * H2;
    float Hi = c1i * H1 + c2i * H2;
    float Pr = c1r * Psi1 + c2r * Psi2;
    float Pi = c1i * Psi1 + c2i * Psi2;
    float Sr = Pr;
    float Si = -Pi;

    s_hr += (double)(Sr * Hr - Si * Hi);
    s_hi += (double)(Sr * Hi + Si * Hr);
    s_pr += (double)(Sr * Pr - Si * Pi);
    s_pi += (double)(Sr * Pi + Si * Pr);
}

__device__ __forceinline__ void pair_accum(
    const float4* __restrict__ Rs4, int j,
    float Z, float k1, float k2,
    float c1r, float c1i, float c2r, float c2i,
    double& s0, double& s1, double& s2, double& s3)
{
    float4 v0 = Rs4[3*j + 0];
    float4 v1 = Rs4[3*j + 1];
    float4 v2 = Rs4[3*j + 2];
    walker_accum(v0.x, v0.y, v0.z, v0.w, v1.x, v1.y,
                 Z, k1, k2, c1r, c1i, c2r, c2i, s0, s1, s2, s3);
    walker_accum(v1.z, v1.w, v2.x, v2.y, v2.z, v2.w,
                 Z, k1, k2, c1r, c1i, c2r, c2i, s0, s1, s2, s3);
}

__global__ __launch_bounds__(BLOCK) void wvfn_fused(
    const float4* __restrict__ Rs4,   // float4 view of [N,2,3] f32
    const float* __restrict__ a_p,
    const float* __restrict__ c1r_p, const float* __restrict__ c1i_p,
    const float* __restrict__ c2r_p, const float* __restrict__ c2i_p,
    double* __restrict__ partials,    // SoA: [4][GRID] in d_ws
    unsigned int* __restrict__ counter,
    float* __restrict__ out, int out_size, int npairs)
{
    const float Z   = 1.0f / a_p[0];
    const float c1r = c1r_p[0], c1i = c1i_p[0];
    const float c2r = c2r_p[0], c2i = c2i_p[0];
    const float Y00 = 0.28209479177387814f;            // 1/sqrt(4*pi)
    const float Zs  = Z * sqrtf(Z);                    // Z^1.5
    const float k1  = 2.0f * Zs * Y00;
    const float k2  = Zs * 0.3535533905932738f * Y00;  // 1/(2*sqrt(2))

    double s0 = 0.0, s1 = 0.0, s2 = 0.0, s3 = 0.0;

    const int tid    = blockIdx.x * BLOCK + threadIdx.x;
    const int stride = GRID * BLOCK;

    // 2x unrolled grid-stride: 6 float4 loads in flight before compute
    int j = tid;
    for (; j + stride < npairs; j += 2 * stride) {
        int j2 = j + stride;
        float4 a0 = Rs4[3*j  + 0];
        float4 a1 = Rs4[3*j  + 1];
        float4 a2 = Rs4[3*j  + 2];
        float4 b0 = Rs4[3*j2 + 0];
        float4 b1 = Rs4[3*j2 + 1];
        float4 b2 = Rs4[3*j2 + 2];
        walker_accum(a0.x, a0.y, a0.z, a0.w, a1.x, a1.y,
                     Z, k1, k2, c1r, c1i, c2r, c2i, s0, s1, s2, s3);
        walker_accum(a1.z, a1.w, a2.x, a2.y, a2.z, a2.w,
                     Z, k1, k2, c1r, c1i, c2r, c2i, s0, s1, s2, s3);
        walker_accum(b0.x, b0.y, b0.z, b0.w, b1.x, b1.y,
                     Z, k1, k2, c1r, c1i, c2r, c2i, s0, s1, s2, s3);
        walker_accum(b1.z, b1.w, b2.x, b2.y, b2.z, b2.w,
                     Z, k1, k2, c1r, c1i, c2r, c2i, s0, s1, s2, s3);
    }
    if (j < npairs) {
        pair_accum(Rs4, j, Z, k1, k2, c1r, c1i, c2r, c2i, s0, s1, s2, s3);
    }

    // wave(64) butterfly reduce
    for (int off = 32; off > 0; off >>= 1) {
        s0 += __shfl_down(s0, off);
        s1 += __shfl_down(s1, off);
        s2 += __shfl_down(s2, off);
        s3 += __shfl_down(s3, off);
    }

    __shared__ double sm[4][BLOCK / 64];
    __shared__ bool isLast;
    int wid  = threadIdx.x >> 6;
    int lane = threadIdx.x & 63;
    if (lane == 0) { sm[0][wid] = s0; sm[1][wid] = s1; sm[2][wid] = s2; sm[3][wid] = s3; }
    __syncthreads();
    if (threadIdx.x == 0) {
        double t0 = 0, t1 = 0, t2 = 0, t3 = 0;
        for (int w = 0; w < BLOCK / 64; ++w) {
            t0 += sm[0][w]; t1 += sm[1][w]; t2 += sm[2][w]; t3 += sm[3][w];
        }
        // agent-scope (device-coherent) stores: safe across non-coherent XCD L2s
        __hip_atomic_store(&partials[0 * GRID + blockIdx.x], t0,
                           __ATOMIC_RELEASE, __HIP_MEMORY_SCOPE_AGENT);
        __hip_atomic_store(&partials[1 * GRID + blockIdx.x], t1,
                           __ATOMIC_RELEASE, __HIP_MEMORY_SCOPE_AGENT);
        __hip_atomic_store(&partials[2 * GRID + blockIdx.x], t2,
                           __ATOMIC_RELEASE, __HIP_MEMORY_SCOPE_AGENT);
        __hip_atomic_store(&partials[3 * GRID + blockIdx.x], t3,
                           __ATOMIC_RELEASE, __HIP_MEMORY_SCOPE_AGENT);
        __threadfence();
        unsigned int prev = atomicAdd(counter, 1u);
        isLast = (prev == (unsigned int)(GRID - 1));
    }
    __syncthreads();

    if (isLast) {
        __threadfence();   // acquire: invalidate stale cached lines
        double t0 = 0, t1 = 0, t2 = 0, t3 = 0;
        for (int b = threadIdx.x; b < GRID; b += BLOCK) {
            t0 += __hip_atomic_load(&partials[0 * GRID + b],
                                    __ATOMIC_ACQUIRE, __HIP_MEMORY_SCOPE_AGENT);
            t1 += __hip_atomic_load(&partials[1 * GRID + b],
                                    __ATOMIC_ACQUIRE, __HIP_MEMORY_SCOPE_AGENT);
            t2 += __hip_atomic_load(&partials[2 * GRID + b],
                                    __ATOMIC_ACQUIRE, __HIP_MEMORY_SCOPE_AGENT);
            t3 += __hip_atomic_load(&partials[3 * GRID + b],
                                    __ATOMIC_ACQUIRE, __HIP_MEMORY_SCOPE_AGENT);
        }
        for (int off = 32; off > 0; off >>= 1) {
            t0 += __shfl_down(t0, off);
            t1 += __shfl_down(t1, off);
            t2 += __shfl_down(t2, off);
            t3 += __shfl_down(t3, off);
        }
        if (lane == 0) { sm[0][wid] = t0; sm[1][wid] = t1; sm[2][wid] = t2; sm[3][wid] = t3; }
        __syncthreads();
        if (threadIdx.x == 0) {
            double u0 = 0, u1 = 0, u2 = 0, u3 = 0;
            for (int w = 0; w < BLOCK / 64; ++w) {
                u0 += sm[0][w]; u1 += sm[1][w]; u2 += sm[2][w]; u3 += sm[3][w];
            }
            // result = (u0 + i u1) / (u2 + i u3)  (1/N mean factors cancel)
            double den = u2 * u2 + u3 * u3;
            double rr  = (u0 * u2 + u1 * u3) / den;
            double ri  = (u1 * u2 - u0 * u3) / den;
            out[0] = (float)rr;
            if (out_size > 1) out[1] = (float)ri;
        }
    }
}

extern "C" void kernel_launch(void* const* d_in, const int* in_sizes, int n_in,
                              void* d_out, int out_size, void* d_ws, size_t ws_size,
                              hipStream_t stream) {
    const float4* Rs4 = (const float4*)d_in[0];
    const float* a_p  = (const float*)d_in[1];
    const float* c1r  = (const float*)d_in[2];
    const float* c1i  = (const float*)d_in[3];
    const float* c2r  = (const float*)d_in[4];
    const float* c2i  = (const float*)d_in[5];

    int N      = in_sizes[0] / 6;   // [N,2,3] f32 -> N walkers
    int npairs = N / 2;

    // d_ws layout: [4*GRID doubles][counter]
    double*       partials = (double*)d_ws;
    unsigned int* counter  = (unsigned int*)((char*)d_ws + 4 * GRID * sizeof(double));

    // reset semaphore each call (graph-capture-legal; poison leaves 0xAA..)
    hipMemsetAsync(counter, 0, sizeof(unsigned int), stream);

    wvfn_fused<<<GRID, BLOCK, 0, stream>>>(Rs4, a_p, c1r, c1i, c2r, c2i,
                                           partials, counter,
                                           (float*)d_out, out_size, npairs);
}

// Round 5
// 21.894 us; speedup vs baseline: 4.2596x; 4.2596x over previous
//
#include <hip/hip_runtime.h>
#include <math.h>

#define BLOCK  256
#define GRID   1024
#define NCOMP  7

// Per-walker evaluation with HW approx intrinsics.
// Accumulates 7 real moments: a11 += Psi1*H1, a22 += Psi2*H2, a12 += Psi1*H2,
// a21 += Psi2*H1, p11 += Psi1^2, p22 += Psi2^2, p12 += Psi1*Psi2.
__device__ __forceinline__ void walker_accum(
    float x0, float y0, float z0, float x1, float y1, float z1,
    float Z, float zz, float ch, float K1, float K2,
    float& a11, float& a22, float& a12, float& a21,
    float& p11, float& p22, float& p12)
{
    float rr0 = x0*x0 + y0*y0 + z0*z0;
    float rr1 = x1*x1 + y1*y1 + z1*z1;
    float q0  = __builtin_amdgcn_rsqf(rr0);      // 1/r0
    float q1  = __builtin_amdgcn_rsqf(rr1);      // 1/r1
    float r0  = rr0 * q0;
    float r1  = rr1 * q1;

    // h = exp(-0.5 Z r) = 2^(ch * r),  ch = -0.5 Z log2(e)
    float h0 = __builtin_amdgcn_exp2f(ch * r0);
    float h1 = __builtin_amdgcn_exp2f(ch * r1);
    float hh = h0 * h1;

    float Psi1 = K1 * (hh * hh);                          // prod psi100
    float Psi2 = K2 * (2.0f - Z*r0) * (2.0f - Z*r1) * hh; // prod psi200

    float sinv = q0 + q1;

    float dx = x0 - x1, dy = y0 - y1, dz = z0 - z1;
    float dd = dx*dx + dy*dy + dz*dz;
    float V  = -__builtin_amdgcn_rsqf(dd);       // -1/d12  (VB = 1)

    // -0.5*lap1 = Z*sinv - Z^2 ; -0.5*lap2 = Z*sinv - 0.25 Z^2
    float t1 = Z * sinv - zz + V;
    float t2 = Z * sinv - 0.25f * zz + V;
    float H1 = t1 * Psi1;
    float H2 = t2 * Psi2;

    a11 += Psi1 * H1;
    a22 += Psi2 * H2;
    a12 += Psi1 * H2;
    a21 += Psi2 * H1;
    p11 += Psi1 * Psi1;
    p22 += Psi2 * Psi2;
    p12 += Psi1 * Psi2;
}

__global__ __launch_bounds__(BLOCK) void wvfn_partial(
    const float4* __restrict__ Rs4,   // float4 view of [N,2,3] f32
    const float* __restrict__ a_p,
    double* __restrict__ partials,    // SoA: [NCOMP][GRID]
    int npairs)
{
    const float Z  = 1.0f / a_p[0];
    const float zz = Z * Z;
    const float ch = -0.5f * Z * 1.4426950408889634f;   // -0.5 Z log2(e)
    const float Y00sq = 0.07957747154594767f;           // 1/(4*pi)
    const float Z3 = Z * zz;
    const float K1 = 4.0f * Z3 * Y00sq;                 // (2 Z^1.5 Y00)^2
    const float K2 = 0.125f * Z3 * Y00sq;               // (Z^1.5 Y00 / (2 sqrt 2))^2

    float a11 = 0.f, a22 = 0.f, a12 = 0.f, a21 = 0.f;
    float p11 = 0.f, p22 = 0.f, p12 = 0.f;

    const int tid    = blockIdx.x * BLOCK + threadIdx.x;
    const int stride = GRID * BLOCK;
    for (int j = tid; j < npairs; j += stride) {
        float4 v0 = Rs4[3*j + 0];
        float4 v1 = Rs4[3*j + 1];
        float4 v2 = Rs4[3*j + 2];
        // walker 2j  : particle0 (v0.x v0.y v0.z), particle1 (v0.w v1.x v1.y)
        // walker 2j+1: particle0 (v1.z v1.w v2.x), particle1 (v2.y v2.z v2.w)
        walker_accum(v0.x, v0.y, v0.z, v0.w, v1.x, v1.y,
                     Z, zz, ch, K1, K2, a11, a22, a12, a21, p11, p22, p12);
        walker_accum(v1.z, v1.w, v2.x, v2.y, v2.z, v2.w,
                     Z, zz, ch, K1, K2, a11, a22, a12, a21, p11, p22, p12);
    }

    double s[NCOMP] = { (double)a11, (double)a22, (double)a12, (double)a21,
                        (double)p11, (double)p22, (double)p12 };

    // wave(64) butterfly reduce
    for (int off = 32; off > 0; off >>= 1) {
        #pragma unroll
        for (int c = 0; c < NCOMP; ++c) s[c] += __shfl_down(s[c], off);
    }

    __shared__ double sm[NCOMP][BLOCK / 64];
    int wid  = threadIdx.x >> 6;
    int lane = threadIdx.x & 63;
    if (lane == 0) {
        #pragma unroll
        for (int c = 0; c < NCOMP; ++c) sm[c][wid] = s[c];
    }
    __syncthreads();
    if (threadIdx.x == 0) {
        #pragma unroll
        for (int c = 0; c < NCOMP; ++c) {
            double t = 0.0;
            for (int w = 0; w < BLOCK / 64; ++w) t += sm[c][w];
            partials[c * GRID + blockIdx.x] = t;
        }
    }
}

__global__ __launch_bounds__(BLOCK) void wvfn_finish(
    const double* __restrict__ partials,   // SoA: [NCOMP][GRID]
    const float* __restrict__ c1r_p, const float* __restrict__ c1i_p,
    const float* __restrict__ c2r_p, const float* __restrict__ c2i_p,
    float* __restrict__ out, int out_size)
{
    double s[NCOMP];
    #pragma unroll
    for (int c = 0; c < NCOMP; ++c) s[c] = 0.0;
    for (int b = threadIdx.x; b < GRID; b += BLOCK) {
        #pragma unroll
        for (int c = 0; c < NCOMP; ++c) s[c] += partials[c * GRID + b];
    }
    for (int off = 32; off > 0; off >>= 1) {
        #pragma unroll
        for (int c = 0; c < NCOMP; ++c) s[c] += __shfl_down(s[c], off);
    }
    __shared__ double sm[NCOMP][BLOCK / 64];
    int wid  = threadIdx.x >> 6;
    int lane = threadIdx.x & 63;
    if (lane == 0) {
        #pragma unroll
        for (int c = 0; c < NCOMP; ++c) sm[c][wid] = s[c];
    }
    __syncthreads();
    if (threadIdx.x == 0) {
        double A11 = 0, A22 = 0, A12 = 0, A21 = 0, P11 = 0, P22 = 0, P12 = 0;
        for (int w = 0; w < BLOCK / 64; ++w) {
            A11 += sm[0][w]; A22 += sm[1][w]; A12 += sm[2][w]; A21 += sm[3][w];
            P11 += sm[4][w]; P22 += sm[5][w]; P12 += sm[6][w];
        }
        // psistar*H_psi = |c1|^2 A11 + |c2|^2 A22 + conj(c1)c2 A12 + c1 conj(c2) A21
        // psistar*psi   = |c1|^2 P11 + |c2|^2 P22 + 2 Re(conj(c1)c2) P12   (real)
        double c1r = (double)c1r_p[0], c1i = (double)c1i_p[0];
        double c2r = (double)c2r_p[0], c2i = (double)c2i_p[0];
        double m1 = c1r*c1r + c1i*c1i;          // |c1|^2
        double m2 = c2r*c2r + c2i*c2i;          // |c2|^2
        double u  = c1r*c2r + c1i*c2i;          // Re(conj(c1) c2)
        double v  = c1r*c2i - c1i*c2r;          // Im(conj(c1) c2)

        double Hre = m1*A11 + m2*A22 + u*(A12 + A21);
        double Him = v*(A12 - A21);
        double Den = m1*P11 + m2*P22 + 2.0*u*P12;

        out[0] = (float)(Hre / Den);
        if (out_size > 1) out[1] = (float)(Him / Den);
    }
}

extern "C" void kernel_launch(void* const* d_in, const int* in_sizes, int n_in,
                              void* d_out, int out_size, void* d_ws, size_t ws_size,
                              hipStream_t stream) {
    const float4* Rs4 = (const float4*)d_in[0];
    const float* a_p  = (const float*)d_in[1];
    const float* c1r  = (const float*)d_in[2];
    const float* c1i  = (const float*)d_in[3];
    const float* c2r  = (const float*)d_in[4];
    const float* c2i  = (const float*)d_in[5];

    int N      = in_sizes[0] / 6;   // [N,2,3] f32 -> N walkers
    int npairs = N / 2;

    double* partials = (double*)d_ws;   // NCOMP*GRID doubles = 56 KB

    wvfn_partial<<<GRID, BLOCK, 0, stream>>>(Rs4, a_p, partials, npairs);
    wvfn_finish<<<1, BLOCK, 0, stream>>>(partials, c1r, c1i, c2r, c2i,
                                         (float*)d_out, out_size);
}